// Round 21
// baseline (338.123 us; speedup 1.0000x reference)
//
#include <hip/hip_runtime.h>
#include <math.h>

#define B 4
#define T 4096
#define D 256
#define NCH 16
#define CHT (T / NCH)
#define KC 32
#define NCHUNK (T / KC)

typedef __attribute__((ext_vector_type(8))) _Float16 half8;
typedef __attribute__((ext_vector_type(4))) _Float16 half4;
typedef __attribute__((ext_vector_type(4))) float f32x4;

// ---------------------------------------------------------------------------
// Fused prep: blocks [0,192) = instance-norm partial sums;
//             blocks [192,288) = W -> fp16 hi/lo split (2048 elems/block).
// ---------------------------------------------------------------------------
__global__ __launch_bounds__(256) void k_prep(
    const float* __restrict__ fc, const float* __restrict__ fs,
    const float* __restrict__ fcs, float* __restrict__ part,
    const float* __restrict__ Wf, const float* __restrict__ Wg,
    const float* __restrict__ Wh, _Float16* __restrict__ Whi,
    _Float16* __restrict__ Wlo)
{
    int blk = blockIdx.x;
    if (blk < 192) {                      // 3*B*NCH stats-part blocks
        int tensor = blk / (B * NCH);
        int rem = blk % (B * NCH);
        int b = rem / NCH, ch = rem % NCH;
        const float* x = (tensor == 0) ? fc : ((tensor == 1) ? fs : fcs);
        int c = threadIdx.x;
        const float* p = x + ((size_t)b * T + (size_t)ch * CHT) * D + c;
        float s = 0.f, ss = 0.f;
        for (int t = 0; t < CHT; ++t) {
            float v = p[(size_t)t * D];
            s += v; ss += v * v;
        }
        float* o = part + (((size_t)tensor * B + b) * NCH + ch) * 2 * D;
        o[c] = s;
        o[D + c] = ss;
    } else {                              // 96 wprep blocks, 8 elems/thread
        int base = (blk - 192) * 2048;
        #pragma unroll
        for (int i = 0; i < 8; ++i) {
            int idx = base + threadIdx.x + i * 256;   // 0..196607
            int which = idx >> 16, rc = idx & 65535;
            const float* Wsrc = (which == 0) ? Wf : ((which == 1) ? Wg : Wh);
            float v = Wsrc[rc];
            _Float16 h = (_Float16)v;
            float l = v - (float)h;
            Whi[idx] = h;
            Wlo[idx] = (_Float16)l;
        }
    }
}

// ---------------------------------------------------------------------------
// Stage 2: fused triple MFMA projection (stats finalize fused in prologue).
// ---------------------------------------------------------------------------
__global__ __launch_bounds__(256) void k_gemm3(
    const float* __restrict__ fc, const float* __restrict__ fs,
    const _Float16* __restrict__ Whi, const _Float16* __restrict__ Wlo,
    const float* __restrict__ bf, const float* __restrict__ bg,
    const float* __restrict__ bh, const float* __restrict__ part,
    _Float16* __restrict__ Qg, _Float16* __restrict__ Kg,
    _Float16* __restrict__ oV, _Float16* __restrict__ oV2h,
    _Float16* __restrict__ oV2l)
{
    __shared__ _Float16 Xl[64 * 256];
    __shared__ float mean_s[256], rstd_s[256];
    const int which = blockIdx.x >> 8;
    const int m0 = (blockIdx.x & 255) * 64;
    const int b = m0 / T;
    const int tid = threadIdx.x;
    const float* x = (which == 0) ? fc : fs;
    const float* bias = (which == 0) ? bf : ((which == 1) ? bg : bh);
    const _Float16* Wh_ = Whi + which * 65536;
    const _Float16* Wl_ = Wlo + which * 65536;
    const int use_norm = (which != 2);

    if (use_norm) {
        int c = tid;
        const float* pp = part + (((size_t)which * B + b) * NCH) * 2 * D;
        float s = 0.f, ss = 0.f;
        for (int ch = 0; ch < NCH; ++ch) {
            s  += pp[(size_t)ch * 2 * D + c];
            ss += pp[(size_t)ch * 2 * D + D + c];
        }
        float mean = s / (float)T;
        float var  = ss / (float)T - mean * mean;
        mean_s[c] = mean;
        rstd_s[c] = rsqrtf(var + 1e-5f);
    }
    __syncthreads();

    #pragma unroll
    for (int j = 0; j < 16; ++j) {
        int idx = tid + j * 256;
        int m = idx >> 6, c4 = idx & 63;
        float4 v = *(const float4*)(x + ((size_t)(m0 + m)) * D + c4 * 4);
        if (use_norm) {
            int c = c4 * 4;
            v.x = (v.x - mean_s[c + 0]) * rstd_s[c + 0];
            v.y = (v.y - mean_s[c + 1]) * rstd_s[c + 1];
            v.z = (v.z - mean_s[c + 2]) * rstd_s[c + 2];
            v.w = (v.w - mean_s[c + 3]) * rstd_s[c + 3];
        }
        half4 h;
        h[0] = (_Float16)v.x; h[1] = (_Float16)v.y;
        h[2] = (_Float16)v.z; h[3] = (_Float16)v.w;
        *(half4*)&Xl[m * 256 + ((c4 * 4) ^ ((m & 7) << 3))] = h;
    }
    __syncthreads();

    const int l = tid & 63, w = tid >> 6;
    const int lo16 = l & 15, hi4 = l >> 4;
    const int row = w * 16 + lo16;

    float bias_v[16];
    #pragma unroll
    for (int nt = 0; nt < 16; ++nt) bias_v[nt] = bias[nt * 16 + lo16];

    f32x4 acc[16];
    #pragma unroll
    for (int nt = 0; nt < 16; ++nt) acc[nt] = (f32x4){0.f, 0.f, 0.f, 0.f};

    #pragma unroll
    for (int kk = 0; kk < 8; ++kk) {
        half8 a = *(const half8*)&Xl[row * 256 + ((kk * 32 + hi4 * 8) ^ ((row & 7) << 3))];
        #pragma unroll
        for (int nt = 0; nt < 16; ++nt) {
            size_t wo = (size_t)(nt * 16 + lo16) * 256 + kk * 32 + hi4 * 8;
            half8 bhf = *(const half8*)(Wh_ + wo);
            acc[nt] = __builtin_amdgcn_mfma_f32_16x16x32_f16(a, bhf, acc[nt], 0, 0, 0);
            half8 blf = *(const half8*)(Wl_ + wo);
            acc[nt] = __builtin_amdgcn_mfma_f32_16x16x32_f16(a, blf, acc[nt], 0, 0, 0);
        }
    }

    if (which != 2) {
        _Float16* out1 = (which == 0) ? Qg : Kg;
        #pragma unroll
        for (int nt = 0; nt < 16; ++nt)
            #pragma unroll
            for (int r = 0; r < 4; ++r) {
                int t = m0 + w * 16 + hi4 * 4 + r;
                out1[(size_t)t * D + nt * 16 + lo16] = (_Float16)(acc[nt][r] + bias_v[nt]);
            }
    } else {
        int t0 = (m0 % T) + w * 16 + hi4 * 4;
        #pragma unroll
        for (int nt = 0; nt < 16; ++nt) {
            int o = nt * 16 + lo16;
            half4 vh, h4, l4;
            #pragma unroll
            for (int r = 0; r < 4; ++r) {
                float v = acc[nt][r] + bias_v[nt];
                _Float16 vhh = (_Float16)v;
                float f2 = (float)vhh * (float)vhh;    // exact in fp32
                _Float16 hh = (_Float16)f2;
                float fl = f2 - (float)hh;             // exact residual
                vh[r] = vhh; h4[r] = hh; l4[r] = (_Float16)fl;
            }
            size_t base = ((size_t)b * D + o) * T + t0;
            *(half4*)(oV   + base) = vh;
            *(half4*)(oV2h + base) = h4;
            *(half4*)(oV2l + base) = l4;
        }
    }
}

// ---------------------------------------------------------------------------
// Stage 3: fp16 MFMA flash attention — R20 structure with ALL THREE V
// streams (V, V2h, V2l) consumed as DIRECT-GLOBAL PV B-frags: each wave
// loads its 6 frags (2 d-tiles x 3 streams) at the TOP of slot kc and
// consumes them at the END of the slot in PV(kc-1). Never held across a
// barrier; V data is static and L2-resident (XCD swizzle). LDS now holds
// only K (double-buffered) + P + small state (~45 KB); B-waves stage only K.
// Per-accumulator FP op sequence bitwise-identical to rounds 5-20.
// ---------------------------------------------------------------------------
__global__ __launch_bounds__(512, 1) void k_attn(
    const _Float16* __restrict__ Qg, const _Float16* __restrict__ Kg,
    const _Float16* __restrict__ Vtg, const _Float16* __restrict__ V2hg,
    const _Float16* __restrict__ V2lg, const float* __restrict__ fcs,
    const float* __restrict__ part, float* __restrict__ out)
{
    __shared__ __align__(16) _Float16 Kl [2][32 * 256];  // [key][d] swizzled
    __shared__ __align__(16) _Float16 Pl [2][64 * 32];
    __shared__ float corr_lds[2][64];
    __shared__ float l_lds[64];
    __shared__ int   flags[2][4];
    __shared__ float mfc_s[256], rfc_s[256];

    const int tid = threadIdx.x;
    const int l = tid & 63;
    const int w = tid >> 6;               // 0..7
    // XCD swizzle: 256 blocks, 8 XCDs, 32 consecutive per XCD (bijective)
    const int swz = (blockIdx.x & 7) * 32 + (blockIdx.x >> 3);
    const int b  = swz >> 6;
    const int q0 = (swz & 63) << 6;
    const int lo16 = l & 15, hi4 = l >> 4;

    const _Float16* KgB  = Kg   + (size_t)b * T * D;
    const _Float16* VtB  = Vtg  + (size_t)b * D * T;
    const _Float16* V2hB = V2hg + (size_t)b * D * T;
    const _Float16* V2lB = V2lg + (size_t)b * D * T;

    // fcs instance-norm stats for this batch (tensor 2), fused finalize
    if (tid < 256) {
        int c = tid;
        const float* pp = part + (((size_t)2 * B + b) * NCH) * 2 * D;
        float s = 0.f, ss = 0.f;
        for (int ch = 0; ch < NCH; ++ch) {
            s  += pp[(size_t)ch * 2 * D + c];
            ss += pp[(size_t)ch * 2 * D + D + c];
        }
        float mean = s / (float)T;
        float var  = ss / (float)T - mean * mean;
        mfc_s[c] = mean;
        rfc_s[c] = rsqrtf(var + 1e-5f);
    }

    // Q fragments: only QK waves (w<4), rows q0+16w..+16
    half8 qf[8];
    if (w < 4) {
        const _Float16* qp = Qg + ((size_t)(b * T + q0 + 16 * w + lo16)) * D + hi4 * 8;
        #pragma unroll
        for (int kk = 0; kk < 8; ++kk) qf[kk] = *(const half8*)(qp + kk * 32);
    }

    // Direct-global element offsets for this wave's 2 PV d-tiles
    int voff[2];
    #pragma unroll
    for (int jj = 0; jj < 2; ++jj)
        voff[jj] = ((2 * w + jj) * 16 + lo16) * T + hi4 * 8;

    // PV accumulators: [q-subtile][jj]; every wave owns d-tiles 2w, 2w+1
    f32x4 accM[4][2], accE[4][2];
    #pragma unroll
    for (int qs = 0; qs < 4; ++qs)
        #pragma unroll
        for (int jj = 0; jj < 2; ++jj) {
            accM[qs][jj] = (f32x4){0.f, 0.f, 0.f, 0.f};
            accE[qs][jj] = (f32x4){0.f, 0.f, 0.f, 0.f};
        }
    float m_run[4] = {-1e9f, -1e9f, -1e9f, -1e9f};
    float lv[4] = {0.f, 0.f, 0.f, 0.f};          // per-lane partial l (QK waves)

    const int t2 = tid & 255;             // stage lane id (waves 4-7)

    // PV(chunk parity pb): rescale + 24 MFMA; all B-frags from registers
    auto do_pv = [&](int pb, const half8* bhf, const half8* b2h, const half8* b2l) {
        #pragma unroll
        for (int qs = 0; qs < 4; ++qs) {
            if (flags[pb][qs]) {
                #pragma unroll
                for (int r = 0; r < 4; ++r) {
                    float c = corr_lds[pb][qs * 16 + hi4 * 4 + r];
                    accM[qs][0][r] *= c; accM[qs][1][r] *= c;
                    accE[qs][0][r] *= c; accE[qs][1][r] *= c;
                }
            }
        }
        half8 pa[4];
        #pragma unroll
        for (int qs = 0; qs < 4; ++qs) {
            int q = qs * 16 + lo16;
            pa[qs] = *(const half8*)&Pl[pb][q * 32 + ((hi4 ^ (q & 3)) << 3)];
        }
        __builtin_amdgcn_s_setprio(1);
        #pragma unroll
        for (int jj = 0; jj < 2; ++jj) {
            #pragma unroll
            for (int qs = 0; qs < 4; ++qs) {
                accM[qs][jj] = __builtin_amdgcn_mfma_f32_16x16x32_f16(pa[qs], bhf[jj], accM[qs][jj], 0, 0, 0);
                accE[qs][jj] = __builtin_amdgcn_mfma_f32_16x16x32_f16(pa[qs], b2h[jj], accE[qs][jj], 0, 0, 0);
                accE[qs][jj] = __builtin_amdgcn_mfma_f32_16x16x32_f16(pa[qs], b2l[jj], accE[qs][jj], 0, 0, 0);
            }
        }
        __builtin_amdgcn_s_setprio(0);
    };

    // prologue (waves 4-7): K(0) -> Kl[0]
    if (w >= 4) {
        half8 kr0[4];
        #pragma unroll
        for (int i = 0; i < 4; ++i) {
            int g = t2 + i * 256;                   // row=g>>5, cg=g&31
            kr0[i] = *(const half8*)(KgB + (size_t)(g >> 5) * D + (g & 31) * 8);
        }
        #pragma unroll
        for (int i = 0; i < 4; ++i) {
            int g = t2 + i * 256; int rr = g >> 5, cg = g & 31;
            *(half8*)&Kl[0][rr * 256 + ((cg ^ (rr & 7)) << 3)] = kr0[i];
        }
    }
    __syncthreads();

    for (int kc = 0; kc < NCHUNK; ++kc) {
        const int cb = kc & 1, pb = cb ^ 1;   // pb == (kc-1)&1 when kc>0

        // ---- V-frags for PV(kc-1): issued at slot top, used at slot end ----
        half8 bhf[2], b2h[2], b2l[2];
        if (kc > 0) {
            int kp = (kc - 1) * KC;
            #pragma unroll
            for (int jj = 0; jj < 2; ++jj) {
                bhf[jj] = *(const half8*)(VtB  + kp + voff[jj]);
                b2h[jj] = *(const half8*)(V2hB + kp + voff[jj]);
                b2l[jj] = *(const half8*)(V2lB + kp + voff[jj]);
            }
        }

        if (w < 4) {
            // ---- QK^T(kc) for this wave's 16 q-rows ----
            f32x4 c0 = (f32x4){0.f, 0.f, 0.f, 0.f}, c1 = (f32x4){0.f, 0.f, 0.f, 0.f};
            __builtin_amdgcn_s_setprio(1);
            #pragma unroll
            for (int kk = 0; kk < 8; ++kk) {
                int cg = kk * 4 + hi4;
                half8 b0 = *(const half8*)&Kl[cb][lo16 * 256 + ((cg ^ (lo16 & 7)) << 3)];
                half8 b1 = *(const half8*)&Kl[cb][(16 + lo16) * 256 + ((cg ^ ((16 + lo16) & 7)) << 3)];
                c0 = __builtin_amdgcn_mfma_f32_16x16x32_f16(qf[kk], b0, c0, 0, 0, 0);
                c1 = __builtin_amdgcn_mfma_f32_16x16x32_f16(qf[kk], b1, c1, 0, 0, 0);
            }
            __builtin_amdgcn_s_setprio(0);

            // ---- PV(kc-1) (independent of QK result; fills the pipe) ----
            if (kc > 0) do_pv(pb, bhf, b2h, b2l);

            // ---- deferred online softmax (kc) ----
            float cm[4];
            #pragma unroll
            for (int r = 0; r < 4; ++r) cm[r] = fmaxf(c0[r], c1[r]);
            float tmax = fmaxf(fmaxf(cm[0] - m_run[0], cm[1] - m_run[1]),
                               fmaxf(cm[2] - m_run[2], cm[3] - m_run[3]));
            int flagv = 0;
            if (__any(tmax > 10.f)) {
                flagv = 1;
                float corr[4];
                #pragma unroll
                for (int r = 0; r < 4; ++r) {
                    float rm = cm[r];
                    rm = fmaxf(rm, __shfl_xor(rm, 1));
                    rm = fmaxf(rm, __shfl_xor(rm, 2));
                    rm = fmaxf(rm, __shfl_xor(rm, 4));
                    rm = fmaxf(rm, __shfl_xor(rm, 8));
                    float mn = fmaxf(m_run[r], rm);
                    corr[r] = __expf(m_run[r] - mn);
                    m_run[r] = mn;
                    lv[r] *= corr[r];
                }
                if (lo16 == 0) {
                    #pragma unroll
                    for (int r = 0; r < 4; ++r)
                        corr_lds[cb][w * 16 + hi4 * 4 + r] = corr[r];
                }
            }
            if (l == 0) flags[cb][w] = flagv;

            float p0[4], p1[4];
            #pragma unroll
            for (int r = 0; r < 4; ++r) {
                p0[r] = __expf(c0[r] - m_run[r]);   // bounded by e^10 < fp16 max
                p1[r] = __expf(c1[r] - m_run[r]);
                lv[r] += p0[r] + p1[r];
            }
            // ---- P(kc) -> Pl[cb] ----
            #pragma unroll
            for (int r = 0; r < 4; ++r) {
                int q = 16 * w + hi4 * 4 + r;
                int ka = lo16, kb = 16 + lo16;
                Pl[cb][q * 32 + (((ka >> 3) ^ (q & 3)) << 3) + (ka & 7)] = (_Float16)p0[r];
                Pl[cb][q * 32 + (((kb >> 3) ^ (q & 3)) << 3) + (kb & 7)] = (_Float16)p1[r];
            }
        } else {
            // ---- issue K(kc+1) loads EARLY ----
            half8 kr[4];
            const bool doK = (kc + 1 < NCHUNK);
            if (doK) {
                int kn = (kc + 1) * KC;
                #pragma unroll
                for (int i = 0; i < 4; ++i) {
                    int g = t2 + i * 256;
                    kr[i] = *(const half8*)(KgB + (size_t)(kn + (g >> 5)) * D + (g & 31) * 8);
                }
            }

            // ---- PV(kc-1) while loads fly ----
            if (kc > 0) do_pv(pb, bhf, b2h, b2l);

            // ---- commit K(kc+1) LATE (Kl[cb^1]; QK(kc) read Kl[cb]) ----
            if (doK) {
                #pragma unroll
                for (int i = 0; i < 4; ++i) {
                    int g = t2 + i * 256; int rr = g >> 5, cg = g & 31;
                    *(half8*)&Kl[cb ^ 1][rr * 256 + ((cg ^ (rr & 7)) << 3)] = kr[i];
                }
            }
        }
        __syncthreads();                  // single barrier per chunk
    }

    // ---- tail: PV(NCHUNK-1) ----
    {
        half8 bhf[2], b2h[2], b2l[2];
        int kp = (NCHUNK - 1) * KC;
        #pragma unroll
        for (int jj = 0; jj < 2; ++jj) {
            bhf[jj] = *(const half8*)(VtB  + kp + voff[jj]);
            b2h[jj] = *(const half8*)(V2hB + kp + voff[jj]);
            b2l[jj] = *(const half8*)(V2lB + kp + voff[jj]);
        }
        do_pv((NCHUNK - 1) & 1, bhf, b2h, b2l);
    }

    // ---- l broadcast ----
    if (w < 4) {
        #pragma unroll
        for (int r = 0; r < 4; ++r) {
            float lr = lv[r];
            lr += __shfl_xor(lr, 1);
            lr += __shfl_xor(lr, 2);
            lr += __shfl_xor(lr, 4);
            lr += __shfl_xor(lr, 8);
            if (lo16 == 0) l_lds[w * 16 + hi4 * 4 + r] = lr;
        }
    }
    __syncthreads();

    // ---- fused epilogue ----
    #pragma unroll
    for (int qs = 0; qs < 4; ++qs) {
        #pragma unroll
        for (int r = 0; r < 4; ++r) {
            float linv = 1.f / l_lds[qs * 16 + hi4 * 4 + r];
            int q = q0 + qs * 16 + hi4 * 4 + r;
            size_t rowb = ((size_t)(b * T + q)) * D;
            #pragma unroll
            for (int jj = 0; jj < 2; ++jj) {
                int d = (2 * w + jj) * 16 + lo16;
                float M  = accM[qs][jj][r] * linv;
                float E2 = accE[qs][jj][r] * linv;
                float S  = sqrtf(fmaxf(E2 - M * M, 1e-6f));
                float f  = fcs[rowb + d];
                out[rowb + d] = S * ((f - mfc_s[d]) * rfc_s[d]) + M;
            }
        }
    }
}

// ---------------------------------------------------------------------------
extern "C" void kernel_launch(void* const* d_in, const int* in_sizes, int n_in,
                              void* d_out, int out_size, void* d_ws, size_t ws_size,
                              hipStream_t stream)
{
    const float* fc  = (const float*)d_in[0];
    const float* fs  = (const float*)d_in[1];
    const float* fcs = (const float*)d_in[2];
    const float* Wf  = (const float*)d_in[3];
    const float* bf  = (const float*)d_in[4];
    const float* Wg  = (const float*)d_in[5];
    const float* bg  = (const float*)d_in[6];
    const float* Wh  = (const float*)d_in[7];
    const float* bh  = (const float*)d_in[8];
    float* out = (float*)d_out;

    char* ws = (char*)d_ws;
    float* part  = (float*)(ws + (64 << 10));            // 384 KB
    _Float16* Whi = (_Float16*)(ws + (512 << 10));       // 3*128 KB
    _Float16* Wlo = Whi + 3 * 65536;                     // 3*128 KB
    _Float16* Qg   = (_Float16*)(ws + (2 << 20));        // 8 MB each
    _Float16* Kg   = Qg  + (size_t)B * T * D;
    _Float16* Vtg  = Kg  + (size_t)B * T * D;
    _Float16* V2hg = Vtg + (size_t)B * T * D;
    _Float16* V2lg = V2hg + (size_t)B * T * D;

    k_prep<<<288, 256, 0, stream>>>(fc, fs, fcs, part, Wf, Wg, Wh, Whi, Wlo);

    k_gemm3<<<3 * 256, 256, 0, stream>>>(fc, fs, Whi, Wlo, bf, bg, bh, part,
                                         Qg, Kg, Vtg, V2hg, V2lg);

    k_attn<<<B * (T / 64), 512, 0, stream>>>(Qg, Kg, Vtg, V2hg, V2lg, fcs, part, out);
}

// Round 22
// 298.200 us; speedup vs baseline: 1.1339x; 1.1339x over previous
//
#include <hip/hip_runtime.h>
#include <math.h>

#define B 4
#define T 4096
#define D 256
#define NCH 16
#define CHT (T / NCH)
#define KC 32
#define NCHUNK (T / KC)

typedef __attribute__((ext_vector_type(8))) _Float16 half8;
typedef __attribute__((ext_vector_type(4))) _Float16 half4;
typedef __attribute__((ext_vector_type(4))) float f32x4;

// ---------------------------------------------------------------------------
// Fused prep: blocks [0,192) = instance-norm partial sums;
//             blocks [192,288) = W -> fp16 hi/lo split (2048 elems/block).
// ---------------------------------------------------------------------------
__global__ __launch_bounds__(256) void k_prep(
    const float* __restrict__ fc, const float* __restrict__ fs,
    const float* __restrict__ fcs, float* __restrict__ part,
    const float* __restrict__ Wf, const float* __restrict__ Wg,
    const float* __restrict__ Wh, _Float16* __restrict__ Whi,
    _Float16* __restrict__ Wlo)
{
    int blk = blockIdx.x;
    if (blk < 192) {                      // 3*B*NCH stats-part blocks
        int tensor = blk / (B * NCH);
        int rem = blk % (B * NCH);
        int b = rem / NCH, ch = rem % NCH;
        const float* x = (tensor == 0) ? fc : ((tensor == 1) ? fs : fcs);
        int c = threadIdx.x;
        const float* p = x + ((size_t)b * T + (size_t)ch * CHT) * D + c;
        float s = 0.f, ss = 0.f;
        for (int t = 0; t < CHT; ++t) {
            float v = p[(size_t)t * D];
            s += v; ss += v * v;
        }
        float* o = part + (((size_t)tensor * B + b) * NCH + ch) * 2 * D;
        o[c] = s;
        o[D + c] = ss;
    } else {                              // 96 wprep blocks, 8 elems/thread
        int base = (blk - 192) * 2048;
        #pragma unroll
        for (int i = 0; i < 8; ++i) {
            int idx = base + threadIdx.x + i * 256;   // 0..196607
            int which = idx >> 16, rc = idx & 65535;
            const float* Wsrc = (which == 0) ? Wf : ((which == 1) ? Wg : Wh);
            float v = Wsrc[rc];
            _Float16 h = (_Float16)v;
            float l = v - (float)h;
            Whi[idx] = h;
            Wlo[idx] = (_Float16)l;
        }
    }
}

// ---------------------------------------------------------------------------
// Stage 2: fused triple MFMA projection (stats finalize fused in prologue).
// ---------------------------------------------------------------------------
__global__ __launch_bounds__(256) void k_gemm3(
    const float* __restrict__ fc, const float* __restrict__ fs,
    const _Float16* __restrict__ Whi, const _Float16* __restrict__ Wlo,
    const float* __restrict__ bf, const float* __restrict__ bg,
    const float* __restrict__ bh, const float* __restrict__ part,
    _Float16* __restrict__ Qg, _Float16* __restrict__ Kg,
    _Float16* __restrict__ oV, _Float16* __restrict__ oV2h,
    _Float16* __restrict__ oV2l)
{
    __shared__ _Float16 Xl[64 * 256];
    __shared__ float mean_s[256], rstd_s[256];
    const int which = blockIdx.x >> 8;
    const int m0 = (blockIdx.x & 255) * 64;
    const int b = m0 / T;
    const int tid = threadIdx.x;
    const float* x = (which == 0) ? fc : fs;
    const float* bias = (which == 0) ? bf : ((which == 1) ? bg : bh);
    const _Float16* Wh_ = Whi + which * 65536;
    const _Float16* Wl_ = Wlo + which * 65536;
    const int use_norm = (which != 2);

    if (use_norm) {
        int c = tid;
        const float* pp = part + (((size_t)which * B + b) * NCH) * 2 * D;
        float s = 0.f, ss = 0.f;
        for (int ch = 0; ch < NCH; ++ch) {
            s  += pp[(size_t)ch * 2 * D + c];
            ss += pp[(size_t)ch * 2 * D + D + c];
        }
        float mean = s / (float)T;
        float var  = ss / (float)T - mean * mean;
        mean_s[c] = mean;
        rstd_s[c] = rsqrtf(var + 1e-5f);
    }
    __syncthreads();

    #pragma unroll
    for (int j = 0; j < 16; ++j) {
        int idx = tid + j * 256;
        int m = idx >> 6, c4 = idx & 63;
        float4 v = *(const float4*)(x + ((size_t)(m0 + m)) * D + c4 * 4);
        if (use_norm) {
            int c = c4 * 4;
            v.x = (v.x - mean_s[c + 0]) * rstd_s[c + 0];
            v.y = (v.y - mean_s[c + 1]) * rstd_s[c + 1];
            v.z = (v.z - mean_s[c + 2]) * rstd_s[c + 2];
            v.w = (v.w - mean_s[c + 3]) * rstd_s[c + 3];
        }
        half4 h;
        h[0] = (_Float16)v.x; h[1] = (_Float16)v.y;
        h[2] = (_Float16)v.z; h[3] = (_Float16)v.w;
        *(half4*)&Xl[m * 256 + ((c4 * 4) ^ ((m & 7) << 3))] = h;
    }
    __syncthreads();

    const int l = tid & 63, w = tid >> 6;
    const int lo16 = l & 15, hi4 = l >> 4;
    const int row = w * 16 + lo16;

    float bias_v[16];
    #pragma unroll
    for (int nt = 0; nt < 16; ++nt) bias_v[nt] = bias[nt * 16 + lo16];

    f32x4 acc[16];
    #pragma unroll
    for (int nt = 0; nt < 16; ++nt) acc[nt] = (f32x4){0.f, 0.f, 0.f, 0.f};

    #pragma unroll
    for (int kk = 0; kk < 8; ++kk) {
        half8 a = *(const half8*)&Xl[row * 256 + ((kk * 32 + hi4 * 8) ^ ((row & 7) << 3))];
        #pragma unroll
        for (int nt = 0; nt < 16; ++nt) {
            size_t wo = (size_t)(nt * 16 + lo16) * 256 + kk * 32 + hi4 * 8;
            half8 bhf = *(const half8*)(Wh_ + wo);
            acc[nt] = __builtin_amdgcn_mfma_f32_16x16x32_f16(a, bhf, acc[nt], 0, 0, 0);
            half8 blf = *(const half8*)(Wl_ + wo);
            acc[nt] = __builtin_amdgcn_mfma_f32_16x16x32_f16(a, blf, acc[nt], 0, 0, 0);
        }
    }

    if (which != 2) {
        _Float16* out1 = (which == 0) ? Qg : Kg;
        #pragma unroll
        for (int nt = 0; nt < 16; ++nt)
            #pragma unroll
            for (int r = 0; r < 4; ++r) {
                int t = m0 + w * 16 + hi4 * 4 + r;
                out1[(size_t)t * D + nt * 16 + lo16] = (_Float16)(acc[nt][r] + bias_v[nt]);
            }
    } else {
        int t0 = (m0 % T) + w * 16 + hi4 * 4;
        #pragma unroll
        for (int nt = 0; nt < 16; ++nt) {
            int o = nt * 16 + lo16;
            half4 vh, h4, l4;
            #pragma unroll
            for (int r = 0; r < 4; ++r) {
                float v = acc[nt][r] + bias_v[nt];
                _Float16 vhh = (_Float16)v;
                float f2 = (float)vhh * (float)vhh;    // exact in fp32
                _Float16 hh = (_Float16)f2;
                float fl = f2 - (float)hh;             // exact residual
                vh[r] = vhh; h4[r] = hh; l4[r] = (_Float16)fl;
            }
            size_t base = ((size_t)b * D + o) * T + t0;
            *(half4*)(oV   + base) = vh;
            *(half4*)(oV2h + base) = h4;
            *(half4*)(oV2l + base) = l4;
        }
    }
}

// ---------------------------------------------------------------------------
// Stage 3: fp16 MFMA flash attention — R20 structure (V/V2h deep-staged in
// LDS, V2l direct-global in-slot, pipelined PV one chunk behind QK, 1
// barrier/chunk) + A-WAVE QK/PV INTERLEAVE: per kk iteration 2 QK MFMA +
// 3 PV MFMA from a flattened list (8x bh-LDS, then 8x b2h-LDS, then 8x
// b2l-global) — PV fills the QK dependent-chain stalls; b2l first use
// slides ~500 cyc past its issue. Each accumulator's op order unchanged
// -> bitwise-identical output to rounds 5-20.
// ---------------------------------------------------------------------------
__global__ __launch_bounds__(512, 1) void k_attn(
    const _Float16* __restrict__ Qg, const _Float16* __restrict__ Kg,
    const _Float16* __restrict__ Vtg, const _Float16* __restrict__ V2hg,
    const _Float16* __restrict__ V2lg, const float* __restrict__ fcs,
    const float* __restrict__ part, float* __restrict__ out)
{
    __shared__ __align__(16) _Float16 Kl [2][32 * 256];  // [key][d] swizzled
    __shared__ __align__(16) _Float16 Vl [2][256 * 32];  // [d][key] swizzled
    __shared__ __align__(16) _Float16 V2h[2][256 * 32];
    __shared__ __align__(16) _Float16 Pl [2][64 * 32];
    __shared__ float corr_lds[2][64];
    __shared__ float l_lds[64];
    __shared__ int   flags[2][4];
    __shared__ float mfc_s[256], rfc_s[256];

    const int tid = threadIdx.x;
    const int l = tid & 63;
    const int w = tid >> 6;               // 0..7
    // XCD swizzle: 256 blocks, 8 XCDs, 32 consecutive per XCD (bijective)
    const int swz = (blockIdx.x & 7) * 32 + (blockIdx.x >> 3);
    const int b  = swz >> 6;
    const int q0 = (swz & 63) << 6;
    const int lo16 = l & 15, hi4 = l >> 4;

    const _Float16* KgB  = Kg   + (size_t)b * T * D;
    const _Float16* VtB  = Vtg  + (size_t)b * D * T;
    const _Float16* V2hB = V2hg + (size_t)b * D * T;
    const _Float16* V2lB = V2lg + (size_t)b * D * T;

    // fcs instance-norm stats for this batch (tensor 2), fused finalize
    if (tid < 256) {
        int c = tid;
        const float* pp = part + (((size_t)2 * B + b) * NCH) * 2 * D;
        float s = 0.f, ss = 0.f;
        for (int ch = 0; ch < NCH; ++ch) {
            s  += pp[(size_t)ch * 2 * D + c];
            ss += pp[(size_t)ch * 2 * D + D + c];
        }
        float mean = s / (float)T;
        float var  = ss / (float)T - mean * mean;
        mfc_s[c] = mean;
        rfc_s[c] = rsqrtf(var + 1e-5f);
    }

    // Q fragments: only QK waves (w<4), rows q0+16w..+16
    half8 qf[8];
    if (w < 4) {
        const _Float16* qp = Qg + ((size_t)(b * T + q0 + 16 * w + lo16)) * D + hi4 * 8;
        #pragma unroll
        for (int kk = 0; kk < 8; ++kk) qf[kk] = *(const half8*)(qp + kk * 32);
    }

    // V2l direct-global element offsets for this wave's 2 PV d-tiles
    int v2off[2];
    #pragma unroll
    for (int jj = 0; jj < 2; ++jj)
        v2off[jj] = ((2 * w + jj) * 16 + lo16) * T + hi4 * 8;

    // PV accumulators: [q-subtile][jj]; every wave owns d-tiles 2w, 2w+1
    f32x4 accM[4][2], accE[4][2];
    #pragma unroll
    for (int qs = 0; qs < 4; ++qs)
        #pragma unroll
        for (int jj = 0; jj < 2; ++jj) {
            accM[qs][jj] = (f32x4){0.f, 0.f, 0.f, 0.f};
            accE[qs][jj] = (f32x4){0.f, 0.f, 0.f, 0.f};
        }
    float m_run[4] = {-1e9f, -1e9f, -1e9f, -1e9f};
    float lv[4] = {0.f, 0.f, 0.f, 0.f};          // per-lane partial l (QK waves)

    const int t2 = tid & 255;             // stage lane id (waves 4-7)
    // V/V2h stream registers held ACROSS barriers (B-waves; loop-carried)
    half8 vr[4], vhr[4];

    // rescale for chunk parity pb (shared by both wave roles)
    auto do_rescale = [&](int pb) {
        #pragma unroll
        for (int qs = 0; qs < 4; ++qs) {
            if (flags[pb][qs]) {
                #pragma unroll
                for (int r = 0; r < 4; ++r) {
                    float c = corr_lds[pb][qs * 16 + hi4 * 4 + r];
                    accM[qs][0][r] *= c; accM[qs][1][r] *= c;
                    accE[qs][0][r] *= c; accE[qs][1][r] *= c;
                }
            }
        }
    };
    // full PV (rescale + 24 MFMA) — B-waves and tail
    auto do_pv = [&](int pb, const half8* b2l) {
        do_rescale(pb);
        half8 pa[4];
        #pragma unroll
        for (int qs = 0; qs < 4; ++qs) {
            int q = qs * 16 + lo16;
            pa[qs] = *(const half8*)&Pl[pb][q * 32 + ((hi4 ^ (q & 3)) << 3)];
        }
        __builtin_amdgcn_s_setprio(1);
        #pragma unroll
        for (int jj = 0; jj < 2; ++jj) {
            int d = (2 * w + jj) * 16 + lo16;
            int p = d * 32 + ((hi4 ^ ((d >> 1) & 3)) << 3);
            half8 bh  = *(const half8*)&Vl[pb][p];
            half8 b2h = *(const half8*)&V2h[pb][p];
            #pragma unroll
            for (int qs = 0; qs < 4; ++qs) {
                accM[qs][jj] = __builtin_amdgcn_mfma_f32_16x16x32_f16(pa[qs], bh,  accM[qs][jj], 0, 0, 0);
                accE[qs][jj] = __builtin_amdgcn_mfma_f32_16x16x32_f16(pa[qs], b2h, accE[qs][jj], 0, 0, 0);
                accE[qs][jj] = __builtin_amdgcn_mfma_f32_16x16x32_f16(pa[qs], b2l[jj], accE[qs][jj], 0, 0, 0);
            }
        }
        __builtin_amdgcn_s_setprio(0);
    };

    // prologue (waves 4-7): K(0) -> Kl[0]; V/V2h(0) loads -> held registers
    if (w >= 4) {
        half8 kr0[4];
        #pragma unroll
        for (int i = 0; i < 4; ++i) {
            int g = t2 + i * 256;                   // row=g>>5, cg=g&31
            kr0[i] = *(const half8*)(KgB + (size_t)(g >> 5) * D + (g & 31) * 8);
        }
        #pragma unroll
        for (int i = 0; i < 4; ++i) {
            int g = t2 + i * 256; int d = g >> 2, kg = g & 3;
            size_t off = (size_t)d * T + kg * 8;
            vr[i]  = *(const half8*)(VtB  + off);
            vhr[i] = *(const half8*)(V2hB + off);
        }
        #pragma unroll
        for (int i = 0; i < 4; ++i) {
            int g = t2 + i * 256; int rr = g >> 5, cg = g & 31;
            *(half8*)&Kl[0][rr * 256 + ((cg ^ (rr & 7)) << 3)] = kr0[i];
        }
    }
    __syncthreads();

    for (int kc = 0; kc < NCHUNK; ++kc) {
        const int cb = kc & 1, pb = cb ^ 1;   // pb == (kc-1)&1 when kc>0

        // ---- b2l frags for PV(kc-1): issued at slot top ----
        half8 b2l[2];
        if (kc > 0) {
            const _Float16* v2b = V2lB + (kc - 1) * KC;
            b2l[0] = *(const half8*)(v2b + v2off[0]);
            b2l[1] = *(const half8*)(v2b + v2off[1]);
        }

        if (w < 4) {
            f32x4 c0 = (f32x4){0.f, 0.f, 0.f, 0.f}, c1 = (f32x4){0.f, 0.f, 0.f, 0.f};

            if (kc == 0) {
                // plain QK (no PV yet)
                __builtin_amdgcn_s_setprio(1);
                #pragma unroll
                for (int kk = 0; kk < 8; ++kk) {
                    int cg = kk * 4 + hi4;
                    half8 kb0 = *(const half8*)&Kl[cb][lo16 * 256 + ((cg ^ (lo16 & 7)) << 3)];
                    half8 kb1 = *(const half8*)&Kl[cb][(16 + lo16) * 256 + ((cg ^ ((16 + lo16) & 7)) << 3)];
                    c0 = __builtin_amdgcn_mfma_f32_16x16x32_f16(qf[kk], kb0, c0, 0, 0, 0);
                    c1 = __builtin_amdgcn_mfma_f32_16x16x32_f16(qf[kk], kb1, c1, 0, 0, 0);
                }
                __builtin_amdgcn_s_setprio(0);
            } else {
                // ---- fused QK(kc) + PV(kc-1): 2 QK + 3 PV MFMA per kk ----
                do_rescale(pb);                       // before any PV op
                half8 pa[4];
                #pragma unroll
                for (int qs = 0; qs < 4; ++qs) {
                    int q = qs * 16 + lo16;
                    pa[qs] = *(const half8*)&Pl[pb][q * 32 + ((hi4 ^ (q & 3)) << 3)];
                }
                half8 bhv[2], b2h[2];
                #pragma unroll
                for (int jj = 0; jj < 2; ++jj) {
                    int d = (2 * w + jj) * 16 + lo16;
                    int p = d * 32 + ((hi4 ^ ((d >> 1) & 3)) << 3);
                    bhv[jj] = *(const half8*)&Vl[pb][p];
                    b2h[jj] = *(const half8*)&V2h[pb][p];
                }
                __builtin_amdgcn_s_setprio(1);
                #pragma unroll
                for (int kk = 0; kk < 8; ++kk) {
                    int cg = kk * 4 + hi4;
                    half8 kb0 = *(const half8*)&Kl[cb][lo16 * 256 + ((cg ^ (lo16 & 7)) << 3)];
                    half8 kb1 = *(const half8*)&Kl[cb][(16 + lo16) * 256 + ((cg ^ ((16 + lo16) & 7)) << 3)];
                    c0 = __builtin_amdgcn_mfma_f32_16x16x32_f16(qf[kk], kb0, c0, 0, 0, 0);
                    c1 = __builtin_amdgcn_mfma_f32_16x16x32_f16(qf[kk], kb1, c1, 0, 0, 0);
                    // 3 PV ops: t = kk*3+i; t<8: accM(bh); t<16: accE(b2h); else accE(b2l)
                    #pragma unroll
                    for (int i = 0; i < 3; ++i) {
                        int t = kk * 3 + i;
                        if (t < 8) {
                            int qs = t & 3, jj = t >> 2;
                            accM[qs][jj] = __builtin_amdgcn_mfma_f32_16x16x32_f16(pa[qs], bhv[jj], accM[qs][jj], 0, 0, 0);
                        } else if (t < 16) {
                            int k = t - 8; int qs = k & 3, jj = k >> 2;
                            accE[qs][jj] = __builtin_amdgcn_mfma_f32_16x16x32_f16(pa[qs], b2h[jj], accE[qs][jj], 0, 0, 0);
                        } else {
                            int k = t - 16; int qs = k & 3, jj = k >> 2;
                            accE[qs][jj] = __builtin_amdgcn_mfma_f32_16x16x32_f16(pa[qs], b2l[jj], accE[qs][jj], 0, 0, 0);
                        }
                    }
                }
                __builtin_amdgcn_s_setprio(0);
            }

            // ---- deferred online softmax (kc) ----
            float cm[4];
            #pragma unroll
            for (int r = 0; r < 4; ++r) cm[r] = fmaxf(c0[r], c1[r]);
            float tmax = fmaxf(fmaxf(cm[0] - m_run[0], cm[1] - m_run[1]),
                               fmaxf(cm[2] - m_run[2], cm[3] - m_run[3]));
            int flagv = 0;
            if (__any(tmax > 10.f)) {
                flagv = 1;
                float corr[4];
                #pragma unroll
                for (int r = 0; r < 4; ++r) {
                    float rm = cm[r];
                    rm = fmaxf(rm, __shfl_xor(rm, 1));
                    rm = fmaxf(rm, __shfl_xor(rm, 2));
                    rm = fmaxf(rm, __shfl_xor(rm, 4));
                    rm = fmaxf(rm, __shfl_xor(rm, 8));
                    float mn = fmaxf(m_run[r], rm);
                    corr[r] = __expf(m_run[r] - mn);
                    m_run[r] = mn;
                    lv[r] *= corr[r];
                }
                if (lo16 == 0) {
                    #pragma unroll
                    for (int r = 0; r < 4; ++r)
                        corr_lds[cb][w * 16 + hi4 * 4 + r] = corr[r];
                }
            }
            if (l == 0) flags[cb][w] = flagv;

            float p0[4], p1[4];
            #pragma unroll
            for (int r = 0; r < 4; ++r) {
                p0[r] = __expf(c0[r] - m_run[r]);   // bounded by e^10 < fp16 max
                p1[r] = __expf(c1[r] - m_run[r]);
                lv[r] += p0[r] + p1[r];
            }
            // ---- P(kc) -> Pl[cb] ----
            #pragma unroll
            for (int r = 0; r < 4; ++r) {
                int q = 16 * w + hi4 * 4 + r;
                int ka = lo16, kb = 16 + lo16;
                Pl[cb][q * 32 + (((ka >> 3) ^ (q & 3)) << 3) + (ka & 7)] = (_Float16)p0[r];
                Pl[cb][q * 32 + (((kb >> 3) ^ (q & 3)) << 3) + (kb & 7)] = (_Float16)p1[r];
            }
        } else {
            // ---- commit V/V2h(kc) from held registers (loaded a slot ago).
            //      Vl[cb] is not read by anyone this slot (PV(kc-1) uses [pb]). ----
            #pragma unroll
            for (int i = 0; i < 4; ++i) {
                int g = t2 + i * 256; int d = g >> 2, kg = g & 3;
                int p = d * 32 + ((kg ^ ((d >> 1) & 3)) << 3);
                *(half8*)&Vl[cb][p]  = vr[i];
                *(half8*)&V2h[cb][p] = vhr[i];
            }

            // ---- issue loads EARLY: K(kc+1) and V/V2h(kc+1) ----
            half8 kr[4];
            const bool doK = (kc + 1 < NCHUNK);
            if (doK) {
                int kn = (kc + 1) * KC;
                #pragma unroll
                for (int i = 0; i < 4; ++i) {
                    int g = t2 + i * 256;
                    kr[i] = *(const half8*)(KgB + (size_t)(kn + (g >> 5)) * D + (g & 31) * 8);
                }
                #pragma unroll
                for (int i = 0; i < 4; ++i) {
                    int g = t2 + i * 256; int d = g >> 2, kg = g & 3;
                    size_t off = (size_t)d * T + kn + kg * 8;
                    vr[i]  = *(const half8*)(VtB  + off);
                    vhr[i] = *(const half8*)(V2hB + off);
                }
            }

            // ---- PV(kc-1) while loads fly ----
            if (kc > 0) do_pv(pb, b2l);

            // ---- commit K(kc+1) LATE (Kl[cb^1]; QK(kc) read Kl[cb]) ----
            if (doK) {
                #pragma unroll
                for (int i = 0; i < 4; ++i) {
                    int g = t2 + i * 256; int rr = g >> 5, cg = g & 31;
                    *(half8*)&Kl[cb ^ 1][rr * 256 + ((cg ^ (rr & 7)) << 3)] = kr[i];
                }
            }
        }
        __syncthreads();                  // single barrier per chunk
    }

    // ---- tail: PV(NCHUNK-1) ----
    {
        half8 b2l[2];
        const _Float16* v2b = V2lB + (NCHUNK - 1) * KC;
        b2l[0] = *(const half8*)(v2b + v2off[0]);
        b2l[1] = *(const half8*)(v2b + v2off[1]);
        do_pv((NCHUNK - 1) & 1, b2l);
    }

    // ---- l broadcast ----
    if (w < 4) {
        #pragma unroll
        for (int r = 0; r < 4; ++r) {
            float lr = lv[r];
            lr += __shfl_xor(lr, 1);
            lr += __shfl_xor(lr, 2);
            lr += __shfl_xor(lr, 4);
            lr += __shfl_xor(lr, 8);
            if (lo16 == 0) l_lds[w * 16 + hi4 * 4 + r] = lr;
        }
    }
    __syncthreads();

    // ---- fused epilogue ----
    #pragma unroll
    for (int qs = 0; qs < 4; ++qs) {
        #pragma unroll
        for (int r = 0; r < 4; ++r) {
            float linv = 1.f / l_lds[qs * 16 + hi4 * 4 + r];
            int q = q0 + qs * 16 + hi4 * 4 + r;
            size_t rowb = ((size_t)(b * T + q)) * D;
            #pragma unroll
            for (int jj = 0; jj < 2; ++jj) {
                int d = (2 * w + jj) * 16 + lo16;
                float M  = accM[qs][jj][r] * linv;
                float E2 = accE[qs][jj][r] * linv;
                float S  = sqrtf(fmaxf(E2 - M * M, 1e-6f));
                float f  = fcs[rowb + d];
                out[rowb + d] = S * ((f - mfc_s[d]) * rfc_s[d]) + M;
            }
        }
    }
}

// ---------------------------------------------------------------------------
extern "C" void kernel_launch(void* const* d_in, const int* in_sizes, int n_in,
                              void* d_out, int out_size, void* d_ws, size_t ws_size,
                              hipStream_t stream)
{
    const float* fc  = (const float*)d_in[0];
    const float* fs  = (const float*)d_in[1];
    const float* fcs = (const float*)d_in[2];
    const float* Wf  = (const float*)d_in[3];
    const float* bf  = (const float*)d_in[4];
    const float* Wg  = (const float*)d_in[5];
    const float* bg  = (const float*)d_in[6];
    const float* Wh  = (const float*)d_in[7];
    const float* bh  = (const float*)d_in[8];
    float* out = (float*)d_out;

    char* ws = (char*)d_ws;
    float* part  = (float*)(ws + (64 << 10));            // 384 KB
    _Float16* Whi = (_Float16*)(ws + (512 << 10));       // 3*128 KB
    _Float16* Wlo = Whi + 3 * 65536;                     // 3*128 KB
    _Float16* Qg   = (_Float16*)(ws + (2 << 20));        // 8 MB each
    _Float16* Kg   = Qg  + (size_t)B * T * D;
    _Float16* Vtg  = Kg  + (size_t)B * T * D;
    _Float16* V2hg = Vtg + (size_t)B * T * D;
    _Float16* V2lg = V2hg + (size_t)B * T * D;

    k_prep<<<288, 256, 0, stream>>>(fc, fs, fcs, part, Wf, Wg, Wh, Whi, Wlo);

    k_gemm3<<<3 * 256, 256, 0, stream>>>(fc, fs, Whi, Wlo, bf, bg, bh, part,
                                         Qg, Kg, Vtg, V2hg, V2lg);

    k_attn<<<B * (T / 64), 512, 0, stream>>>(Qg, Kg, Vtg, V2hg, V2lg, fcs, part, out);
}